// Round 2
// baseline (308.728 us; speedup 1.0000x reference)
//
#include <hip/hip_runtime.h>

// SSIM loss, round 9: 32x64 tile (halo amortization), 4-col phase-2 tasks,
// row-rotated H layout (bank-conflict fix for H writes), packed a4/b12.
// imgs: (32, 3, 512, 512) fp32. Output: scalar 1 - mean(ssim_map).
//
// Per block: 32 wide x 64 tall output tile, fp32 throughout.
//  phase 1: stage 74x48 (x1,x2)-interleaved v2f tile (float4 global loads).
//  phase 2: 592 tasks = 74 rows x 8 col-QUADS. Each task: 8 ds_read_b128
//           (16 v2f slots), computes 4 columns' {a01,a23} + packed a4 pairs.
//           Per-slot sq/cross hoisting. 32B LDS read per output column
//           (was 56B with 2-col tasks).
//  barrier; H arrays OVERLAY staging. Layout: h0123 v4f[74][32] + h4
//           f32[74][32] with per-row 16B ROTATION: physical col =
//           (logical + (r&7)) & 31. This spreads phase-2 write bank-starts
//           over all 8 slots (the round-8 fused layout had only 2 -> the
//           12.9M conflict count).
//  phase 3: vertical blur, 8 consecutive rows/thread (2.25 H-row reads per
//           output vs 3.5 at 4 rows/thread), packed b12 pairs, SSIM with
//           v_rcp_f32, wave reduce, spread atomics.
// LDS union 47,360 B -> 3 blocks/CU (measured occupancy was 4 blocks at
// 32x32; per-block work doubles and barriers per output halve).

#define HH 512
#define WW 512
#define TW 32
#define TH 64
#define IN_ROWS 74
#define S_STRIDE 50         // v2f stride of s12 (even -> b128 alignment holds)
#define HSTRIDE 32          // v4f/f32 stride of H arrays
#define NPLANES 96
#define NPIX 25165824.0f
#define NACC 256
#define NT1 888             // 74 rows * 12 quads
#define NT2 592             // 74 rows * 8 col-quads

// union layout (bytes)
#define H0123_OFF 0                  // v4f [74][32] = 37888
#define H4_OFF 37888                 // f32 [74][32] = 9472
#define UNION_BYTES 47360            // >= s12: v2f[74][50] = 29600

typedef float v2f __attribute__((ext_vector_type(2)));
typedef float v4f __attribute__((ext_vector_type(4)));

__global__ __launch_bounds__(256, 3) void ssim_fused_kernel(
    const float* __restrict__ img1, const float* __restrict__ img2,
    float* __restrict__ acc) {
  __shared__ __align__(16) char ub[UNION_BYTES];
  __shared__ float wsum[4];

  v2f (*s12)[S_STRIDE] = (v2f (*)[S_STRIDE])ub;
  v4f (*h0123)[HSTRIDE] = (v4f (*)[HSTRIDE])(ub + H0123_OFF);
  float (*h4)[HSTRIDE] = (float (*)[HSTRIDE])(ub + H4_OFF);

  const int tid = threadIdx.x;
  const int tx = blockIdx.x * TW;
  const int ty = blockIdx.y * TH;
  const size_t base = (size_t)blockIdx.z * (HH * WW);

  const float g[11] = {
      1.0283800e-03f, 7.5987600e-03f, 3.6000770e-02f, 1.0936072e-01f,
      2.1300560e-01f, 2.6601170e-01f, 2.1300560e-01f, 1.0936072e-01f,
      3.6000770e-02f, 7.5987600e-03f, 1.0283800e-03f};

  // ---- phase 1: float4 staging, interleave (x1,x2) into s12 ----
  // pixel slot = gx - (tx-8); 74 rows x 12 quads; quads 16B-aligned in global.
#pragma unroll
  for (int it = 0; it < 4; ++it) {
    int idx = it * 256 + tid;
    if (idx < NT1) {
      int r = idx / 12;
      int p = idx - r * 12;
      int gy = ty - 5 + r;
      int gx = tx - 8 + 4 * p;
      v4f A = {0.f, 0.f, 0.f, 0.f}, B = {0.f, 0.f, 0.f, 0.f};
      if ((unsigned)gy < (unsigned)HH && (unsigned)gx < (unsigned)WW) {
        size_t off = base + (size_t)gy * WW + gx;
        A = *(const v4f*)(img1 + off);
        B = *(const v4f*)(img2 + off);
      }
      *(v4f*)&s12[r][4 * p]     = (v4f){A.x, B.x, A.y, B.y};
      *(v4f*)&s12[r][4 * p + 2] = (v4f){A.z, B.z, A.w, B.w};
    }
  }
  __syncthreads();

  // ---- phase 2: horizontal blur, 4 output cols per task ----
  // task (r, cq): c = 4*cq; col c+j taps slots c+3+j .. c+13+j.
  // Read slots c+2..c+17 as 8 b128. Slot i (= slot c+2+i): tap index for
  // col j is k = i-1-j in [0,10]. sq/cross computed once per slot.
  v2f h01h[3][4], h23h[3][4], h4h[3][2];
#pragma unroll
  for (int t = 0; t < 3; ++t) {
    int idx = t * 256 + tid;
    if (idx < NT2) {
      int r = idx >> 3;
      int cq = idx & 7;
      int c = cq << 2;
      const v4f* qp = (const v4f*)&s12[r][c + 2];   // 16B-aligned
      v4f q[8];
#pragma unroll
      for (int m = 0; m < 8; ++m) q[m] = qp[m];
      v2f P[16];
#pragma unroll
      for (int m = 0; m < 8; ++m) {
        P[2 * m]     = (v2f){q[m].x, q[m].y};
        P[2 * m + 1] = (v2f){q[m].z, q[m].w};
      }

      v2f a01[4], a23[4], a4p[2];
#pragma unroll
      for (int j = 0; j < 4; ++j) {
        a01[j] = (v2f){0.f, 0.f};
        a23[j] = (v2f){0.f, 0.f};
      }
      a4p[0] = (v2f){0.f, 0.f};
      a4p[1] = (v2f){0.f, 0.f};

#pragma unroll
      for (int i = 0; i < 16; ++i) {
        v2f p = P[i];
        v2f sq = p * p;
        float cr = p.x * p.y;
#pragma unroll
        for (int j = 0; j < 4; ++j) {
          int k = i - 1 - j;
          if (k >= 0 && k <= 10) {
            float w = g[k];
            a01[j] += w * p;
            a23[j] += w * sq;
          }
        }
        {
          int k0 = i - 1, k1 = i - 2;
          bool u0 = (k0 >= 0 && k0 <= 10), u1 = (k1 >= 0 && k1 <= 10);
          if (u0 || u1) {
            v2f w2 = (v2f){u0 ? g[k0] : 0.f, u1 ? g[k1] : 0.f};
            a4p[0] += w2 * cr;
          }
          int k2 = i - 3, k3 = i - 4;
          bool u2 = (k2 >= 0 && k2 <= 10), u3 = (k3 >= 0 && k3 <= 10);
          if (u2 || u3) {
            v2f w2 = (v2f){u2 ? g[k2] : 0.f, u3 ? g[k3] : 0.f};
            a4p[1] += w2 * cr;
          }
        }
      }
#pragma unroll
      for (int j = 0; j < 4; ++j) {
        h01h[t][j] = a01[j];
        h23h[t][j] = a23[j];
      }
      h4h[t][0] = a4p[0];
      h4h[t][1] = a4p[1];
    }
  }
  __syncthreads();   // all s12 reads done; overlay H on the union

  // rotated H writes: physical col = (logical + (r&7)) & 31 (16B granules)
#pragma unroll
  for (int t = 0; t < 3; ++t) {
    int idx = t * 256 + tid;
    if (idx < NT2) {
      int r = idx >> 3;
      int cq = idx & 7;
      int rot = r & 7;
#pragma unroll
      for (int j = 0; j < 4; ++j) {
        int pc = ((cq << 2) + j + rot) & 31;
        h0123[r][pc] = (v4f){h01h[t][j].x, h01h[t][j].y,
                             h23h[t][j].x, h23h[t][j].y};
      }
      int pg = (cq + rot) & 7;
      *(v4f*)&h4[r][pg << 2] = (v4f){h4h[t][0].x, h4h[t][0].y,
                                     h4h[t][1].x, h4h[t][1].y};
    }
  }
  __syncthreads();

  // ---- phase 3: vertical blur, 8 consecutive rows/thread ----
  const float C1 = 1e-4f;
  const float C2 = 9e-4f;
  const int c = tid & 31;
  const int r0 = (tid >> 5) << 3;

  v2f m[8], vv[8], b12p[4];
#pragma unroll
  for (int o = 0; o < 8; ++o) {
    m[o] = (v2f){0.f, 0.f};
    vv[o] = (v2f){0.f, 0.f};
  }
#pragma unroll
  for (int pr = 0; pr < 4; ++pr) b12p[pr] = (v2f){0.f, 0.f};

#pragma unroll
  for (int dy = 0; dy < 18; ++dy) {
    int rr = r0 + dy;
    int rot = rr & 7;
    int pc = (c + rot) & 31;
    v4f q = h0123[rr][pc];
    float d = h4[rr][((((c >> 2) + rot) & 7) << 2) + (c & 3)];
    v2f a = (v2f){q.x, q.y};
    v2f b = (v2f){q.z, q.w};
#pragma unroll
    for (int o = 0; o < 8; ++o) {
      int k = dy - o;
      if (k >= 0 && k <= 10) {
        float w = g[k];
        m[o] += w * a;
        vv[o] += w * b;
      }
    }
#pragma unroll
    for (int pr = 0; pr < 4; ++pr) {
      int k0 = dy - 2 * pr, k1 = k0 - 1;
      bool u0 = (k0 >= 0 && k0 <= 10), u1 = (k1 >= 0 && k1 <= 10);
      if (u0 || u1) {
        v2f w2 = (v2f){u0 ? g[k0] : 0.f, u1 ? g[k1] : 0.f};
        b12p[pr] += w2 * d;
      }
    }
  }

  float lsum = 0.f;
#pragma unroll
  for (int o = 0; o < 8; ++o) {
    float mu1 = m[o].x, mu2 = m[o].y;
    float mu1sq = mu1 * mu1;
    float mu2sq = mu2 * mu2;
    float mu12 = mu1 * mu2;
    float b12 = (o & 1) ? b12p[o >> 1].y : b12p[o >> 1].x;
    float sig11 = vv[o].x - mu1sq;
    float sig22 = vv[o].y - mu2sq;
    float sig12 = b12 - mu12;
    float num = (2.f * mu12 + C1) * (2.f * sig12 + C2);
    float den = (mu1sq + mu2sq + C1) * (sig11 + sig22 + C2);
    lsum += num * __builtin_amdgcn_rcpf(den);
  }

  // wave reduction + one atomic per block into spread slots
#pragma unroll
  for (int off = 32; off > 0; off >>= 1)
    lsum += __shfl_down(lsum, off, 64);
  const int lane = tid & 63;
  const int wid = tid >> 6;
  if (lane == 0) wsum[wid] = lsum;
  __syncthreads();
  if (tid == 0) {
    float b = wsum[0] + wsum[1] + wsum[2] + wsum[3];
    int slot = (blockIdx.x + blockIdx.y * 16 + blockIdx.z) & (NACC - 1);
    atomicAdd(acc + slot, b);
  }
}

__global__ void ssim_finalize_kernel(const float* __restrict__ acc,
                                     float* __restrict__ out) {
  __shared__ float wsum[4];
  const int tid = threadIdx.x;
  float s = acc[tid];
#pragma unroll
  for (int off = 32; off > 0; off >>= 1)
    s += __shfl_down(s, off, 64);
  if ((tid & 63) == 0) wsum[tid >> 6] = s;
  __syncthreads();
  if (tid == 0)
    out[0] = 1.0f - (wsum[0] + wsum[1] + wsum[2] + wsum[3]) * (1.0f / NPIX);
}

extern "C" void kernel_launch(void* const* d_in, const int* in_sizes, int n_in,
                              void* d_out, int out_size, void* d_ws, size_t ws_size,
                              hipStream_t stream) {
  const float* img1 = (const float*)d_in[0];
  const float* img2 = (const float*)d_in[1];
  float* out = (float*)d_out;
  float* acc = (float*)d_ws;

  (void)hipMemsetAsync(acc, 0, NACC * sizeof(float), stream);

  dim3 grid(WW / TW, HH / TH, NPLANES);   // 16 x 8 x 96 = 12288
  ssim_fused_kernel<<<grid, 256, 0, stream>>>(img1, img2, acc);
  ssim_finalize_kernel<<<1, NACC, 0, stream>>>(acc, out);
}

// Round 3
// 248.103 us; speedup vs baseline: 1.2444x; 1.2444x over previous
//
#include <hip/hip_runtime.h>

// SSIM loss, round 10: round-8 structure (32x32 tile, 4 blocks/CU sweet spot)
// + 4-stream H {mu1, mu2, S=E[x^2+y^2], C=E[xy]} + stride-33 H layout.
// imgs: (32, 3, 512, 512) fp32. Output: scalar 1 - mean(ssim_map).
//
// Round-9 lesson: 64-tall tile -> 3 blocks/CU -> VALUBusy 75->48. Reverted.
// Round-8 lesson: fused-H stride 32 v4f = 512B = 0 mod 128B -> 16-way bank
//   conflict on H writes (12.9M). Fix: stride 33 v4f (528B = 16 mod 128).
// Algebraic: SSIM needs only sig11+sig22, so blur x^2+y^2 as ONE stream S,
//   pack {S, C=E[xy]} as an even-aligned v2f -> taps are 2 packed FMAs
//   (was 2 pk + 1 scalar over 5 lanes). H is one v4f -> phase 3 reads one
//   ds_read_b128 per row (h4 array + addressing deleted).
//
//  phase 1: stage 42x48 (x1,x2)-interleaved v2f tile (float4 global loads).
//  phase 2: 672 tasks = 42 rows x 16 col-pairs; 7 ds_read_b128 per task;
//           per-slot {sq, sc} hoisting; 2 cols via shifted weights; results
//           held in registers across the barrier.
//  barrier; H (v4f[42][33]) OVERLAYS the staging union; 2 b128 writes/task.
//  phase 3: vertical blur, 4 consecutive rows/thread, one b128 read per dy,
//           2 pk FMAs per (dy,o), SSIM with v_rcp_f32, wave reduce,
//           spread atomics.

#define HH 512
#define WW 512
#define TILE 32
#define IN_ROWS 42
#define S_STRIDE 50         // v2f stride of s12 (even -> b128 alignment holds)
#define HSTRIDE 33          // v4f stride of H (odd*16B = 16 mod 128 -> rotate)
#define NPLANES 96
#define NPIX 25165824.0f
#define NACC 256
#define NTASK 672           // 42 rows * 16 col-pairs

#define UNION_BYTES (IN_ROWS * HSTRIDE * 16)   // 22176 >= s12 (16800)

typedef float v2f __attribute__((ext_vector_type(2)));
typedef float v4f __attribute__((ext_vector_type(4)));

__global__ __launch_bounds__(256, 6) void ssim_fused_kernel(
    const float* __restrict__ img1, const float* __restrict__ img2,
    float* __restrict__ acc) {
  __shared__ __align__(16) char ub[UNION_BYTES];
  __shared__ float wsum[4];

  v2f (*s12)[S_STRIDE] = (v2f (*)[S_STRIDE])ub;
  v4f (*h)[HSTRIDE] = (v4f (*)[HSTRIDE])ub;

  const int tid = threadIdx.x;
  const int tx = blockIdx.x * TILE;
  const int ty = blockIdx.y * TILE;
  const size_t base = (size_t)blockIdx.z * (HH * WW);

  const float g[11] = {
      1.0283800e-03f, 7.5987600e-03f, 3.6000770e-02f, 1.0936072e-01f,
      2.1300560e-01f, 2.6601170e-01f, 2.1300560e-01f, 1.0936072e-01f,
      3.6000770e-02f, 7.5987600e-03f, 1.0283800e-03f};

  // ---- phase 1: float4 staging, interleave (x1,x2) into s12 ----
  // pixel slot = gx - (tx-8); 42 rows x 12 quads; quads 16B-aligned in global.
#pragma unroll
  for (int it = 0; it < 2; ++it) {
    int idx = it * 256 + tid;
    if (idx < IN_ROWS * 12) {
      int r = idx / 12;
      int p = idx - r * 12;
      int gy = ty - 5 + r;
      int gx = tx - 8 + 4 * p;
      v4f A = {0.f, 0.f, 0.f, 0.f}, B = {0.f, 0.f, 0.f, 0.f};
      if ((unsigned)gy < (unsigned)HH && (unsigned)gx < (unsigned)WW) {
        size_t off = base + (size_t)gy * WW + gx;
        A = *(const v4f*)(img1 + off);
        B = *(const v4f*)(img2 + off);
      }
      *(v4f*)&s12[r][4 * p]     = (v4f){A.x, B.x, A.y, B.y};
      *(v4f*)&s12[r][4 * p + 2] = (v4f){A.z, B.z, A.w, B.w};
    }
  }
  __syncthreads();

  // ---- phase 2: horizontal blur, 2 output cols per task, b128 tap reads ----
  // task (r, cp): c = 2*cp; taps for col c are pixel slots c+3..c+13,
  // for col c+1 slots c+4..c+14. Read slots c+2..c+15 as 7 b128.
  // Per-slot: sq = p*p (pk), sc = {sq.x+sq.y, p.x*p.y}; both cols consume.
  v4f holdw[3][2];
#pragma unroll
  for (int t = 0; t < 3; ++t) {
    int idx = t * 256 + tid;
    if (idx < NTASK) {
      int r = idx >> 4;
      int c = (idx & 15) * 2;
      const v4f* qp = (const v4f*)&s12[r][c + 2];   // 16B-aligned
      v4f q0 = qp[0], q1 = qp[1], q2 = qp[2], q3 = qp[3];
      v4f q4 = qp[4], q5 = qp[5], q6 = qp[6];
      v2f P[14];
      P[0]  = (v2f){q0.x, q0.y};  P[1]  = (v2f){q0.z, q0.w};
      P[2]  = (v2f){q1.x, q1.y};  P[3]  = (v2f){q1.z, q1.w};
      P[4]  = (v2f){q2.x, q2.y};  P[5]  = (v2f){q2.z, q2.w};
      P[6]  = (v2f){q3.x, q3.y};  P[7]  = (v2f){q3.z, q3.w};
      P[8]  = (v2f){q4.x, q4.y};  P[9]  = (v2f){q4.z, q4.w};
      P[10] = (v2f){q5.x, q5.y};  P[11] = (v2f){q5.z, q5.w};
      P[12] = (v2f){q6.x, q6.y};  P[13] = (v2f){q6.z, q6.w};

      v2f a01_0 = (v2f){0.f, 0.f}, asc_0 = (v2f){0.f, 0.f};
      v2f a01_1 = (v2f){0.f, 0.f}, asc_1 = (v2f){0.f, 0.f};
#pragma unroll
      for (int k = 1; k <= 12; ++k) {
        v2f p = P[k];
        v2f sq = p * p;
        v2f sc = (v2f){sq.x + sq.y, p.x * p.y};
        if (k <= 11) {               // col0 taps slots 1..11, weight g[k-1]
          float w = g[k - 1];
          a01_0 += w * p;
          asc_0 += w * sc;
        }
        if (k >= 2) {                // col1 taps slots 2..12, weight g[k-2]
          float w = g[k - 2];
          a01_1 += w * p;
          asc_1 += w * sc;
        }
      }
      holdw[t][0] = (v4f){a01_0.x, a01_0.y, asc_0.x, asc_0.y};
      holdw[t][1] = (v4f){a01_1.x, a01_1.y, asc_1.x, asc_1.y};
    }
  }
  __syncthreads();   // all s12 reads done; overlay H on the union

#pragma unroll
  for (int t = 0; t < 3; ++t) {
    int idx = t * 256 + tid;
    if (idx < NTASK) {
      int r = idx >> 4;
      int c = (idx & 15) * 2;
      h[r][c]     = holdw[t][0];
      h[r][c + 1] = holdw[t][1];
    }
  }
  __syncthreads();

  // ---- phase 3: vertical blur, 4 consecutive rows/thread, 2 pk FMA/(dy,o) --
  const float C1 = 1e-4f;
  const float C2 = 9e-4f;
  const int c = tid & 31;
  const int r0 = (tid >> 5) * 4;

  v2f m[4], msc[4];
#pragma unroll
  for (int o = 0; o < 4; ++o) {
    m[o] = (v2f){0.f, 0.f};
    msc[o] = (v2f){0.f, 0.f};
  }

#pragma unroll
  for (int dy = 0; dy < 14; ++dy) {
    v4f q = h[r0 + dy][c];           // one ds_read_b128
    v2f a = (v2f){q.x, q.y};
    v2f sc = (v2f){q.z, q.w};
#pragma unroll
    for (int o = 0; o < 4; ++o) {
      const int k = dy - o;
      if (k >= 0 && k < 11) {
        float w = g[k];
        m[o] += w * a;               // pk fma
        msc[o] += w * sc;            // pk fma
      }
    }
  }

  float lsum = 0.f;
#pragma unroll
  for (int o = 0; o < 4; ++o) {
    float mu1 = m[o].x, mu2 = m[o].y;
    float S = msc[o].x, C = msc[o].y;
    float mu1sq = mu1 * mu1;
    float mu2sq = mu2 * mu2;
    float mu12 = mu1 * mu2;
    float sig12 = C - mu12;
    float sigs = S - mu1sq - mu2sq;  // sig11 + sig22
    float num = (2.f * mu12 + C1) * (2.f * sig12 + C2);
    float den = (mu1sq + mu2sq + C1) * (sigs + C2);
    lsum += num * __builtin_amdgcn_rcpf(den);
  }

  // wave reduction + one atomic per block into spread slots
#pragma unroll
  for (int off = 32; off > 0; off >>= 1)
    lsum += __shfl_down(lsum, off, 64);
  const int lane = tid & 63;
  const int wid = tid >> 6;
  if (lane == 0) wsum[wid] = lsum;
  __syncthreads();
  if (tid == 0) {
    float b = wsum[0] + wsum[1] + wsum[2] + wsum[3];
    int slot = (blockIdx.x + blockIdx.y * 16 + blockIdx.z) & (NACC - 1);
    atomicAdd(acc + slot, b);
  }
}

__global__ void ssim_finalize_kernel(const float* __restrict__ acc,
                                     float* __restrict__ out) {
  __shared__ float wsum[4];
  const int tid = threadIdx.x;
  float s = acc[tid];
#pragma unroll
  for (int off = 32; off > 0; off >>= 1)
    s += __shfl_down(s, off, 64);
  if ((tid & 63) == 0) wsum[tid >> 6] = s;
  __syncthreads();
  if (tid == 0)
    out[0] = 1.0f - (wsum[0] + wsum[1] + wsum[2] + wsum[3]) * (1.0f / NPIX);
}

extern "C" void kernel_launch(void* const* d_in, const int* in_sizes, int n_in,
                              void* d_out, int out_size, void* d_ws, size_t ws_size,
                              hipStream_t stream) {
  const float* img1 = (const float*)d_in[0];
  const float* img2 = (const float*)d_in[1];
  float* out = (float*)d_out;
  float* acc = (float*)d_ws;

  (void)hipMemsetAsync(acc, 0, NACC * sizeof(float), stream);

  dim3 grid(WW / TILE, HH / TILE, NPLANES);   // 16 x 16 x 96 = 24576
  ssim_fused_kernel<<<grid, 256, 0, stream>>>(img1, img2, acc);
  ssim_finalize_kernel<<<1, NACC, 0, stream>>>(acc, out);
}